// Round 5
// baseline (339.543 us; speedup 1.0000x reference)
//
#include <hip/hip_runtime.h>

// Problem constants (fixed by setup_inputs)
#define Bb 32
#define Cc 4
#define Hh 512
#define Ww 512
#define Tt 64
#define HW (Hh * Ww)                          // 262144
#define NTOT ((long long)Bb * Cc * Hh * Ww)   // 33,554,432 elements / tensor
// Hot streaming kernel geometry: 2048 blocks x 4 waves x 8 batches x 2 KB
//   = 134,217,728 bytes per stream (exact cover of each tensor)
#define HOT_GRID 2048
#define BLOCK 256
#define NBATCH 8
#define BATCH_B 2048                          // bytes per stream per batch
#define WAVE_BYTES (NBATCH * BATCH_B)         // 16 KB per stream per wave
#define NWAVES (HOT_GRID * 4)                 // 8192

// ws layout:
//   [0 .. 64K)        : double wpartials[8192]  (one per wave)
//   [64K .. 64K+2K)   : double mpartials[256]   (masked-sum partials)
//   [72K .. 72K+1M)   : uint64 rowmask[B*H][8]
#define MPART_OFF   65536
#define ROWMASK_OFF 73728
#define NMPART 256

// s_waitcnt immediates (gfx9 layout): vmcnt[3:0] | expcnt<<4 | lgkmcnt<<8
#define WAITCNT_VM4 0x0F74   // vmcnt(4), expcnt/lgkm no-wait
#define WAITCNT_VM0 0x0F70   // vmcnt(0)

typedef const __attribute__((address_space(1))) unsigned int* gptr_t;
typedef __attribute__((address_space(3))) unsigned int* lptr_t;

// ---------------------------------------------------------------------------
// Kernel 1: per-(b,h) column bitmask (union of token boxes), 8 u64 words/row.
// ---------------------------------------------------------------------------
__global__ __launch_bounds__(256) void build_rowmask_kernel(
    const float* __restrict__ pos,              // [B, T, 2] (x, y)
    unsigned long long* __restrict__ rowmask)   // [B*H][8]
{
    int b   = blockIdx.x;
    int tid = threadIdx.x;

    __shared__ int s_ylo[Tt], s_yhi[Tt], s_xlo[Tt], s_xhi[Tt];
    if (tid < Tt) {
        const float2 xy = ((const float2*)pos)[b * Tt + tid];
        bool valid = (xy.x > 0.0f) && (xy.y > 0.0f);
        int xp = (int)floorf(xy.x * (float)Ww);
        int yp = (int)floorf(xy.y * (float)Hh);
        int xlo = xp - 5; if (xlo < 0) xlo = 0;
        int xhi = xp + 5; if (xhi > Ww) xhi = Ww;
        if (!valid) { xlo = 0; xhi = 0; }
        s_ylo[tid] = valid ? yp - 5 : (1 << 30);
        s_yhi[tid] = valid ? yp + 5 : -(1 << 30);
        s_xlo[tid] = xlo;
        s_xhi[tid] = xhi;
    }
    __syncthreads();

#pragma unroll
    for (int r = 0; r < 2; ++r) {
        int h = 2 * tid + r;
        unsigned long long m[8];
#pragma unroll
        for (int i = 0; i < 8; ++i) m[i] = 0ull;

        for (int t = 0; t < Tt; ++t) {
            if (h < s_ylo[t] || h >= s_yhi[t]) continue;
            int xlo = s_xlo[t], xhi = s_xhi[t];
            if (xlo >= xhi) continue;
            int w0 = xlo >> 6;
            int w1 = (xhi - 1) >> 6;
            for (int wd = w0; wd <= w1; ++wd) {
                int lo = xlo - (wd << 6); if (lo < 0) lo = 0;
                int hi = xhi - (wd << 6); if (hi > 64) hi = 64;
                m[wd] |= (((1ull << (hi - lo)) - 1ull) << lo);
            }
        }

        ulonglong2* out = (ulonglong2*)(rowmask + ((size_t)b * Hh + h) * 8);
#pragma unroll
        for (int i = 0; i < 4; ++i)
            out[i] = make_ulonglong2(m[2 * i], m[2 * i + 1]);
    }
}

// ---------------------------------------------------------------------------
// Kernel 2 (HOT): pure dual-stream sum of diff^2 via global_load_lds DMA.
// Wave-private LDS double buffer (8 KB/wave, 32 KB/block), manual vmcnt.
// No mask logic here; no __syncthreads (no barrier drain).
// ---------------------------------------------------------------------------
__global__ __launch_bounds__(256) void stream_sq_sum_kernel(
    const char* __restrict__ pred,
    const char* __restrict__ targ,
    double* __restrict__ wpartials)
{
    __shared__ char smem[4 * 8192];             // 4 waves x (2 bufs x 4 KB)
    const int tid  = threadIdx.x;
    const int lane = tid & 63;
    const int wid  = tid >> 6;
    const int W    = blockIdx.x * 4 + wid;      // global wave id

    const char* pbase = pred + (size_t)W * WAVE_BYTES;
    const char* tbase = targ + (size_t)W * WAVE_BYTES;
    char* my = smem + wid * 8192;               // wave-private region
    // buf layout: [0,2K)=pred(buf0) [2K,4K)=targ(buf0) [4K,6K)=pred(buf1) [6K,8K)=targ(buf1)

    auto issue_batch = [&](int batch) {
        const int bo = (batch & 1) * 4096;
        const char* p = pbase + batch * BATCH_B;
        const char* t = tbase + batch * BATCH_B;
#pragma unroll
        for (int j = 0; j < 2; ++j)
            __builtin_amdgcn_global_load_lds(
                (gptr_t)(p + j * 1024 + lane * 16),
                (lptr_t)(my + bo + j * 1024), 16, 0, 0);
#pragma unroll
        for (int j = 0; j < 2; ++j)
            __builtin_amdgcn_global_load_lds(
                (gptr_t)(t + j * 1024 + lane * 16),
                (lptr_t)(my + bo + 2048 + j * 1024), 16, 0, 0);
    };

    issue_batch(0);
    issue_batch(1);

    float sfull = 0.f;
#pragma unroll
    for (int i = 0; i < NBATCH; ++i) {
        if (i == NBATCH - 1) __builtin_amdgcn_s_waitcnt(WAITCNT_VM0);
        else                 __builtin_amdgcn_s_waitcnt(WAITCNT_VM4);

        const int bo = (i & 1) * 4096;
        float4 a0 = *(const float4*)(my + bo +    0 + lane * 16);
        float4 a1 = *(const float4*)(my + bo + 1024 + lane * 16);
        float4 b0 = *(const float4*)(my + bo + 2048 + lane * 16);
        float4 b1 = *(const float4*)(my + bo + 3072 + lane * 16);

        float dx, dy, dz, dw;
        dx = a0.x - b0.x; dy = a0.y - b0.y; dz = a0.z - b0.z; dw = a0.w - b0.w;
        sfull += dx * dx; sfull += dy * dy; sfull += dz * dz; sfull += dw * dw;
        dx = a1.x - b1.x; dy = a1.y - b1.y; dz = a1.z - b1.z; dw = a1.w - b1.w;
        sfull += dx * dx; sfull += dy * dy; sfull += dz * dz; sfull += dw * dw;

        if (i + 2 < NBATCH) issue_batch(i + 2);
    }

    // wave-level reduction; one double per wave, no LDS / no atomics
    double v = (double)sfull;
#pragma unroll
    for (int off = 32; off > 0; off >>= 1)
        v += __shfl_down(v, off, 64);
    if (lane == 0) wpartials[W] = v;
}

// ---------------------------------------------------------------------------
// Kernel 3: masked-pixel gather sum. One thread per image row (b,h); walks
// the rowmask bits (avg ~12 set cols/row), sums diff^2 over 4 channels.
// Data is L3-hot; ~6.5 MB unique touched.
// ---------------------------------------------------------------------------
__global__ __launch_bounds__(256) void masked_sum_kernel(
    const float* __restrict__ pred,
    const float* __restrict__ targ,
    const unsigned long long* __restrict__ rowmask,
    double* __restrict__ mpartials)
{
    int row = blockIdx.x * 256 + threadIdx.x;   // 0 .. 16383
    int b = row >> 9;
    int h = row & 511;

    const unsigned long long* rm = rowmask + (size_t)row * 8;
    const float* pb = pred + (size_t)b * (Cc * HW) + (size_t)h * Ww;
    const float* tb = targ + (size_t)b * (Cc * HW) + (size_t)h * Ww;

    float acc = 0.f;
#pragma unroll
    for (int w = 0; w < 8; ++w) {
        unsigned long long word = rm[w];
        while (word) {
            int bit = __builtin_ctzll(word);
            word &= word - 1;
            int c = (w << 6) + bit;
            float d0 = pb[0 * HW + c] - tb[0 * HW + c];
            float d1 = pb[1 * HW + c] - tb[1 * HW + c];
            float d2 = pb[2 * HW + c] - tb[2 * HW + c];
            float d3 = pb[3 * HW + c] - tb[3 * HW + c];
            acc += d0 * d0 + d1 * d1 + d2 * d2 + d3 * d3;
        }
    }

    double v = (double)acc;
#pragma unroll
    for (int off = 32; off > 0; off >>= 1)
        v += __shfl_down(v, off, 64);
    if ((threadIdx.x & 63) == 0)
        mpartials[blockIdx.x * 4 + (threadIdx.x >> 6)] = v;
}

// ---------------------------------------------------------------------------
// Kernel 4: final combine: out = (sum_full + 3*sum_masked) / N
// ---------------------------------------------------------------------------
__global__ __launch_bounds__(256) void final_reduce_kernel(
    const double* __restrict__ wpartials,   // [NWAVES]
    const double* __restrict__ mpartials,   // [NMPART]
    float* __restrict__ out)
{
    int tid = threadIdx.x;
    double v = 0.0;
    for (int i = tid; i < NWAVES; i += 256) v += wpartials[i];
    double m = mpartials[tid];               // NMPART == 256
    double t = v + 3.0 * m;

#pragma unroll
    for (int off = 32; off > 0; off >>= 1)
        t += __shfl_down(t, off, 64);
    __shared__ double lsum[4];
    if ((tid & 63) == 0) lsum[tid >> 6] = t;
    __syncthreads();
    if (tid == 0)
        out[0] = (float)((lsum[0] + lsum[1] + lsum[2] + lsum[3]) *
                         (1.0 / (double)NTOT));
}

extern "C" void kernel_launch(void* const* d_in, const int* in_sizes, int n_in,
                              void* d_out, int out_size, void* d_ws, size_t ws_size,
                              hipStream_t stream) {
    const char*  pred  = (const char*)d_in[0];   // [32,4,512,512] f32
    const char*  targ  = (const char*)d_in[1];
    const float* pos   = (const float*)d_in[3];  // [32,64,2] f32

    double* wpartials = (double*)d_ws;
    double* mpartials = (double*)((char*)d_ws + MPART_OFF);
    unsigned long long* rowmask =
        (unsigned long long*)((char*)d_ws + ROWMASK_OFF);
    float* out = (float*)d_out;

    build_rowmask_kernel<<<Bb, BLOCK, 0, stream>>>(pos, rowmask);
    stream_sq_sum_kernel<<<HOT_GRID, BLOCK, 0, stream>>>(pred, targ, wpartials);
    masked_sum_kernel<<<Bb * Hh / 256, BLOCK, 0, stream>>>(
        (const float*)pred, (const float*)targ, rowmask, mpartials);
    final_reduce_kernel<<<1, 256, 0, stream>>>(wpartials, mpartials, out);
}